// Round 8
// baseline (195.974 us; speedup 1.0000x reference)
//
#include <hip/hip_runtime.h>

#define B_ROWS 14336
#define D_DIM  512
#define C_CLS  7
#define M_CLS  2048

typedef __attribute__((ext_vector_type(4))) float f32x4;

// fp8 scale: fea*64 -> sigma~3.2 in e4m3 range; Gram scaled by 4096
#define FP8_SCALE 64.0f
#define INV_2S2   (2.0f / 4096.0f)

typedef const __attribute__((address_space(1))) char gchar_t;
typedef __attribute__((address_space(3))) char lchar_t;

__device__ __forceinline__ void gload16(const char* g, char* l) {
  // async global->LDS DMA, 16B/lane, dest = wave-uniform base + lane*16
  __builtin_amdgcn_global_load_lds((gchar_t*)g, (lchar_t*)l, 16, 0, 0);
}

// K0: fea->fp8 packed in fragment-order image + row norms + logits + zero zb.
// Image layout: 16B at (r16, kp, l) = byte ((r16*8 + kp)*64 + l)*16, holding
// row r16*16 + (l&15), k-bytes {kp*64 + (l>>4)*8 ..+7} (.x) and {+32..} (.y).
__global__ __launch_bounds__(256) void k_prep(const float* __restrict__ fea,
                                              const float* __restrict__ W,
                                              char* __restrict__ f8p,
                                              float* __restrict__ an,
                                              float* __restrict__ logits,
                                              float* __restrict__ zb) {  // 64 floats
  int t = threadIdx.x, wave = t >> 6, lane = t & 63;
  if (blockIdx.x == 0 && t < 64) zb[t] = 0.f;
  __shared__ char lrow[16 * 528];  // 16 rows x 512B fp8 (+16 pad)

  int r0 = blockIdx.x * 16;
#pragma unroll
  for (int k = 0; k < 4; ++k) {
    int rl = wave * 4 + k;
    int row = r0 + rl;
    const float4* fr4 = (const float4*)(fea + (size_t)row * D_DIM);
    float4 v0 = fr4[lane * 2], v1 = fr4[lane * 2 + 1];

    float p[8];
#pragma unroll
    for (int c = 0; c < 7; ++c) {
      const float4* w4 = (const float4*)(W + c * D_DIM);
      float4 q0 = w4[lane * 2], q1 = w4[lane * 2 + 1];
      p[c] = v0.x * q0.x + v0.y * q0.y + v0.z * q0.z + v0.w * q0.w +
             v1.x * q1.x + v1.y * q1.y + v1.z * q1.z + v1.w * q1.w;
    }
    p[7] = v0.x * v0.x + v0.y * v0.y + v0.z * v0.z + v0.w * v0.w +
           v1.x * v1.x + v1.y * v1.y + v1.z * v1.z + v1.w * v1.w;

#pragma unroll
    for (int c = 0; c < 8; ++c) {
      p[c] += __shfl_xor(p[c], 1);
      p[c] += __shfl_xor(p[c], 2);
      p[c] += __shfl_xor(p[c], 4);
    }
    int v = lane & 7;
    float y = p[0];
    y = (v == 1) ? p[1] : y;
    y = (v == 2) ? p[2] : y;
    y = (v == 3) ? p[3] : y;
    y = (v == 4) ? p[4] : y;
    y = (v == 5) ? p[5] : y;
    y = (v == 6) ? p[6] : y;
    y = (v == 7) ? p[7] : y;
    y += __shfl_xor(y, 8);
    y += __shfl_xor(y, 16);
    y += __shfl_xor(y, 32);
    if (lane < 7) logits[row * 7 + lane] = y;
    else if (lane == 7) an[row] = y;

    int w0 = __builtin_amdgcn_cvt_pk_fp8_f32(v0.x * FP8_SCALE, v0.y * FP8_SCALE, 0, 0);
    w0     = __builtin_amdgcn_cvt_pk_fp8_f32(v0.z * FP8_SCALE, v0.w * FP8_SCALE, w0, 1);
    int w1 = __builtin_amdgcn_cvt_pk_fp8_f32(v1.x * FP8_SCALE, v1.y * FP8_SCALE, 0, 0);
    w1     = __builtin_amdgcn_cvt_pk_fp8_f32(v1.z * FP8_SCALE, v1.w * FP8_SCALE, w1, 1);
    *(int2*)&lrow[rl * 528 + lane * 8] = make_int2(w0, w1);
  }
  __syncthreads();
  int4* outp = (int4*)f8p + (size_t)blockIdx.x * 512;
#pragma unroll
  for (int pi = 0; pi < 2; ++pi) {
    int idx = pi * 256 + t;          // [0,512) = (kp, l)
    int kp = idx >> 6, l = idx & 63;
    int sr = l & 15, qk = l >> 4;
    int2 lo = *(const int2*)&lrow[sr * 528 + kp * 64 + qk * 8];
    int2 hi = *(const int2*)&lrow[sr * 528 + kp * 64 + 32 + qk * 8];
    outp[idx] = make_int4(lo.x, lo.y, hi.x, hi.y);
  }
}

// K1 v8: 256x256 block tile, 8 waves (2Mx4N, wave = 128x64), BK=64,
// double-buffered LDS staged by global_load_lds — round-7 structure — with
// two schedule fixes:
// (1) T4 counted vmcnt + dual RAW barriers per K-tile: STAGE(kt+1) stays in
//     flight across the barrier (s_waitcnt vmcnt(4) waits only for tile kt);
//     no vmcnt(0) drain in the loop. Hazards: barrier B publishes tile kt
//     (each wave waited its own 4 DMAs); barrier A (end of phase) ensures
//     all waves finished ds_reads of buf[cur^1] before next STAGE overwrites
//     it (reads complete at the lgkmcnt(0) before MFMA). asm memory clobbers
//     after each raw barrier pin LDS ops / DMA intrinsics (rule #18).
// (2) XCD-clustered jobs, grid 648 = 81 u x 8 xcd: x<7: u<36 self class x,
//     u in [36,80) cross j = x*44+(u-36); x==7: u<76 cross j = 308+u;
//     u==80: x<7 BN block (class x, 8 wave segments); rest idle.
// rs_part: 48 slots/row: direct tj*4+wc; mirror 32+ti*2+wr.
__global__ __launch_bounds__(512, 2) void k_gram(const char* __restrict__ f8p,
                                                 const float* __restrict__ an,
                                                 const float* __restrict__ logits,
                                                 float* __restrict__ S,
                                                 float* __restrict__ rs_part,
                                                 float* __restrict__ S1,
                                                 float* __restrict__ S2,
                                                 float* __restrict__ aff) {
  int x = blockIdx.x & 7, u = blockIdx.x >> 3;
  int t = threadIdx.x, lane = t & 63, wave = t >> 6;
  if (blockIdx.x == 0 && t == 0) aff[0] = 0.f;

  if (u == 80) {  // BN stats: 7 blocks (x<7), class x, seg = wave
    if (x >= 7) return;
    int c = x, seg = wave;
    int r0 = seg * 1792;
    float s1 = 0.f, s2 = 0.f;
    for (int j = lane; j < 1792; j += 64) {
      float v = logits[(size_t)(r0 + j) * 7 + c];
      s1 += v;
      s2 += v * v;
    }
#pragma unroll
    for (int o = 1; o < 64; o <<= 1) {
      s1 += __shfl_xor(s1, o);
      s2 += __shfl_xor(s2, o);
    }
    if (lane == 0) { atomicAdd(&S1[c], s1); atomicAdd(&S2[c], s2); }
    return;
  }

  int cls1, cls2, ti, tj, Sidx;
  bool self;
  if (x < 7 && u < 36) {
    int a = 0, r = u;
    while (r > a) { r -= a + 1; ++a; }  // u = a(a+1)/2 + r, r<=a
    ti = a; tj = r;                     // tj <= ti
    cls1 = x; cls2 = x; Sidx = x; self = true;
  } else {
    int j;
    if (x < 7) j = x * 44 + (u - 36);          // 0..307
    else { if (u >= 76) return; j = 308 + u; } // 308..383
    int p = j >> 6, t64 = j & 63;
    ti = t64 >> 3; tj = t64 & 7;
    cls1 = p + 1; cls2 = 0; Sidx = 7 + p; self = false;
  }

  __shared__ char ldsA[2][16384];
  __shared__ char ldsB[2][16384];
  __shared__ float bacc[8];

  int R0 = cls1 * 2048 + ti * 256;
  int C0 = cls2 * 2048 + tj * 256;

  // staging: wave stages chunks {2w, 2w+1} of A and B per K-tile
  const char* gA0 = f8p + ((size_t)(R0 >> 4) + wave * 2)     * 8192 + lane * 16;
  const char* gA1 = f8p + ((size_t)(R0 >> 4) + wave * 2 + 1) * 8192 + lane * 16;
  const char* gB0 = f8p + ((size_t)(C0 >> 4) + wave * 2)     * 8192 + lane * 16;
  const char* gB1 = f8p + ((size_t)(C0 >> 4) + wave * 2 + 1) * 8192 + lane * 16;

#define STAGE(kt_, bf_)                                                      \
  do {                                                                       \
    gload16(gA0 + (kt_) * 1024, &ldsA[bf_][(wave * 2) * 1024 + lane * 16]);  \
    gload16(gA1 + (kt_) * 1024, &ldsA[bf_][(wave * 2 + 1) * 1024 + lane * 16]); \
    gload16(gB0 + (kt_) * 1024, &ldsB[bf_][(wave * 2) * 1024 + lane * 16]);  \
    gload16(gB1 + (kt_) * 1024, &ldsB[bf_][(wave * 2 + 1) * 1024 + lane * 16]); \
  } while (0)

  int wr = wave >> 2, wc = wave & 3;   // 2M x 4N wave grid
  int q = lane >> 4, s = lane & 15;

  f32x4 acc[8][4];
#pragma unroll
  for (int i = 0; i < 8; ++i)
#pragma unroll
    for (int j = 0; j < 4; ++j)
      acc[i][j] = (f32x4){0.f, 0.f, 0.f, 0.f};

  STAGE(0, 0);
  __syncthreads();  // prologue: full drain once

#pragma unroll 1
  for (int kt = 0; kt < 8; ++kt) {
    int cur = kt & 1;
    if (kt < 7) {
      STAGE(kt + 1, cur ^ 1);                     // stays in flight across B
      asm volatile("s_waitcnt vmcnt(4)" ::: "memory");  // tile kt landed
    } else {
      asm volatile("s_waitcnt vmcnt(0)" ::: "memory");
    }
    __builtin_amdgcn_s_barrier();                 // B: tile kt visible to all
    asm volatile("" ::: "memory");
    const char* LA = &ldsA[cur][(wr * 8) * 1024 + lane * 16];
    const char* LB = &ldsB[cur][(wc * 4) * 1024 + lane * 16];
    longlong2 a_[8], bb_[4];
#pragma unroll
    for (int i = 0; i < 8; ++i) a_[i] = *(const longlong2*)(LA + i * 1024);
#pragma unroll
    for (int j = 0; j < 4; ++j) bb_[j] = *(const longlong2*)(LB + j * 1024);
    asm volatile("s_waitcnt lgkmcnt(0)" ::: "memory");
    __builtin_amdgcn_sched_barrier(0);            // rule #18
    __builtin_amdgcn_s_setprio(1);
#pragma unroll
    for (int i = 0; i < 8; ++i)
#pragma unroll
      for (int j = 0; j < 4; ++j)
        acc[i][j] = __builtin_amdgcn_mfma_f32_16x16x32_fp8_fp8(
            a_[i].x, bb_[j].x, acc[i][j], 0, 0, 0);
#pragma unroll
    for (int i = 0; i < 8; ++i)
#pragma unroll
      for (int j = 0; j < 4; ++j)
        acc[i][j] = __builtin_amdgcn_mfma_f32_16x16x32_fp8_fp8(
            a_[i].y, bb_[j].y, acc[i][j], 0, 0, 0);
    __builtin_amdgcn_s_setprio(0);
    __builtin_amdgcn_s_barrier();                 // A: all reads of cur done
    asm volatile("" ::: "memory");
  }
#undef STAGE

  // Epilogue. C/D (16x16x32): col=lane&15, row=(lane>>4)*4+reg.
  bool dg = self && (ti == tj);
  bool mirror = self && (ti > tj);
  float blockAcc = 0.f;
  float colAcc[4] = {0.f, 0.f, 0.f, 0.f};
  float anB_[4];
#pragma unroll
  for (int j = 0; j < 4; ++j) anB_[j] = an[C0 + wc * 64 + j * 16 + s];

#pragma unroll
  for (int i = 0; i < 8; ++i) {
    f32x4 anA_ = *(const f32x4*)&an[R0 + wr * 128 + i * 16 + q * 4];
#pragma unroll
    for (int rg = 0; rg < 4; ++rg) {
      int rl = wr * 128 + i * 16 + q * 4 + rg;
      float aA = anA_[rg];
      float rowAcc = 0.f;
#pragma unroll
      for (int j = 0; j < 4; ++j) {
        int cl = wc * 64 + j * 16 + s;
        float g = acc[i][j][rg];
        float d2 = fmaxf(aA + anB_[j] - g * INV_2S2, 0.f);
        if (dg && rl == cl) d2 = 0.f;  // exact diagonal
        float e1 = __expf(-0.05f * d2);
        float e2 = e1 * e1, e4 = e2 * e2, e8 = e4 * e4, e16 = e8 * e8;
        blockAcc += e1 + e2 + e4 + e8 + e16;
        if (self) {
          float ek = __expf(-12.5f * d2);  // KDE: 1/(2*0.2^2)
          rowAcc += ek;
          if (mirror) colAcc[j] += ek;
        }
      }
      if (self) {
        rowAcc += __shfl_xor(rowAcc, 1);
        rowAcc += __shfl_xor(rowAcc, 2);
        rowAcc += __shfl_xor(rowAcc, 4);
        rowAcc += __shfl_xor(rowAcc, 8);
        if (s == 0)
          rs_part[(size_t)(R0 + rl) * 48 + tj * 4 + wc] = rowAcc;
      }
    }
  }
  if (mirror) {
#pragma unroll
    for (int j = 0; j < 4; ++j) {
      float v = colAcc[j];
      v += __shfl_xor(v, 16);
      v += __shfl_xor(v, 32);
      if (q == 0)
        rs_part[(size_t)(C0 + wc * 64 + j * 16 + s) * 48 + 32 + ti * 2 + wr] = v;
    }
    blockAcc *= 2.f;  // mirror tile counted once
  }
#pragma unroll
  for (int o = 1; o < 64; o <<= 1) blockAcc += __shfl_xor(blockAcc, o);
  if (lane == 0) bacc[wave] = blockAcc;
  __syncthreads();
  if (t == 0) {
    float sB = 0.f;
#pragma unroll
    for (int w = 0; w < 8; ++w) sB += bacc[w];
    atomicAdd(&S[Sidx], sB);
  }
}

// K2: bnout (blocks 0..97, 1024 thr) + per-class KDE weight & affinity
// (blocks 98..104). Reads only the valid rs_part slots per block-row bi:
// direct [0, 4bi+4), mirror [34+2bi, 48).
__global__ __launch_bounds__(1024) void k_final(const float* __restrict__ logits,
                                                const float* __restrict__ S1,
                                                const float* __restrict__ S2,
                                                const float* __restrict__ gamma,
                                                const float* __restrict__ beta,
                                                const float* __restrict__ rs_part,
                                                const float* __restrict__ S,
                                                float* __restrict__ out) {
  int b = blockIdx.x, t = threadIdx.x;
  if (b < 98) {
    int idx = b * 1024 + t;  // 98*1024 = 100352 exactly
    int row = idx / 7;
    int c = idx - row * 7;
    float mu = S1[c] * (1.f / 14336.f);
    float var = S2[c] * (1.f / 14336.f) - mu * mu;
    out[idx] = gamma[c] * (logits[idx] - mu) * rsqrtf(var + 1e-5f) + beta[c];
    return;
  }
  int c = b - 98;
  // log_norm = -256*ln(2*pi*0.04) - ln(2048)
  const float LOG_NORM = 345.9110632f;
  float v = 0.f;
  for (int i = t; i < M_CLS; i += 1024) {
    int bi = i >> 8;
    const float* rp = rs_part + (size_t)(c * M_CLS + i) * 48;
    float rsum = 0.f;
    int nd = 4 * bi + 4;
    for (int k = 0; k < nd; ++k) rsum += rp[k];
    for (int k = 34 + 2 * bi; k < 48; ++k) rsum += rp[k];
    v += 1.f / (logf(rsum) + LOG_NORM);
  }
#pragma unroll
  for (int o = 1; o < 64; o <<= 1) v += __shfl_xor(v, o);
  __shared__ float r[16];
  if ((t & 63) == 0) r[t >> 6] = v;
  __syncthreads();
  if (t == 0) {
    float vs = 0.f;
#pragma unroll
    for (int w = 0; w < 16; ++w) vs += r[w];
    float w = 1.f / (vs + 1e-5f);
    const float inv_m2 = 1.0f / ((float)M_CLS * (float)M_CLS);
    float Ssrc = S[c];
    float Stgt = (c > 0) ? S[0] : S[1];
    float X    = (c > 0) ? S[6 + c] : S[7];  // cross Sidx 7+p is (p+1,0)
    float mmd = (Ssrc + Stgt - 2.f * X) * inv_m2;
    atomicAdd(&out[100352], -mmd * w);
  }
}

extern "C" void kernel_launch(void* const* d_in, const int* in_sizes, int n_in,
                              void* d_out, int out_size, void* d_ws, size_t ws_size,
                              hipStream_t stream) {
  const float* fea   = (const float*)d_in[0];
  const float* W_fc  = (const float*)d_in[1];
  const float* gamma = (const float*)d_in[2];
  const float* beta  = (const float*)d_in[3];
  float* out = (float*)d_out;

  char* ws = (char*)d_ws;
  char* f8p = ws;                                // packed fp8 image: 7,340,032 B
  float* fbase   = (float*)(ws + 7340032);
  float* an      = fbase;                        // 14336
  float* logits  = fbase + 14336;                // 100352
  float* zb      = fbase + 114688;               // 64-float zero block
  float* S1      = zb;                           //   [0..6]
  float* S2      = zb + 7;                       //   [7..13]
  float* S       = zb + 16;                      //   [16..28] (13 used)
  float* rs_part = fbase + 114752;               // 14336*48 (valid slots only)

  k_prep <<<896, 256, 0, stream>>>(fea, W_fc, f8p, an, logits, zb);
  k_gram <<<648, 512, 0, stream>>>(f8p, an, logits, S, rs_part, S1, S2,
                                   out + 100352);
  k_final<<<105, 1024, 0, stream>>>(logits, S1, S2, gamma, beta, rs_part, S, out);
}

// Round 10
// 186.292 us; speedup vs baseline: 1.0520x; 1.0520x over previous
//
#include <hip/hip_runtime.h>

#define B_ROWS 14336
#define D_DIM  512
#define C_CLS  7
#define M_CLS  2048

typedef __attribute__((ext_vector_type(4))) float f32x4;

// fp8 scale: fea*64 -> sigma~3.2 in e4m3 range; Gram scaled by 4096
#define FP8_SCALE 64.0f
#define INV_2S2   (2.0f / 4096.0f)

typedef const __attribute__((address_space(1))) char gchar_t;
typedef __attribute__((address_space(3))) char lchar_t;

__device__ __forceinline__ void gload16(const char* g, char* l) {
  // async global->LDS DMA, 16B/lane, dest = wave-uniform base + lane*16
  __builtin_amdgcn_global_load_lds((gchar_t*)g, (lchar_t*)l, 16, 0, 0);
}

// K0: fea->fp8 packed in fragment-order image + row norms + logits + zero zb.
// Image layout: 16B at (r16, kp, l) = byte ((r16*8 + kp)*64 + l)*16, holding
// row r16*16 + (l&15), k-bytes {kp*64 + (l>>4)*8 ..+7} (.x) and {+32..} (.y).
__global__ __launch_bounds__(256) void k_prep(const float* __restrict__ fea,
                                              const float* __restrict__ W,
                                              char* __restrict__ f8p,
                                              float* __restrict__ an,
                                              float* __restrict__ logits,
                                              float* __restrict__ zb) {  // 64 floats
  int t = threadIdx.x, wave = t >> 6, lane = t & 63;
  if (blockIdx.x == 0 && t < 64) zb[t] = 0.f;
  __shared__ char lrow[16 * 528];  // 16 rows x 512B fp8 (+16 pad)

  int r0 = blockIdx.x * 16;
#pragma unroll
  for (int k = 0; k < 4; ++k) {
    int rl = wave * 4 + k;
    int row = r0 + rl;
    const float4* fr4 = (const float4*)(fea + (size_t)row * D_DIM);
    float4 v0 = fr4[lane * 2], v1 = fr4[lane * 2 + 1];

    float p[8];
#pragma unroll
    for (int c = 0; c < 7; ++c) {
      const float4* w4 = (const float4*)(W + c * D_DIM);
      float4 q0 = w4[lane * 2], q1 = w4[lane * 2 + 1];
      p[c] = v0.x * q0.x + v0.y * q0.y + v0.z * q0.z + v0.w * q0.w +
             v1.x * q1.x + v1.y * q1.y + v1.z * q1.z + v1.w * q1.w;
    }
    p[7] = v0.x * v0.x + v0.y * v0.y + v0.z * v0.z + v0.w * v0.w +
           v1.x * v1.x + v1.y * v1.y + v1.z * v1.z + v1.w * v1.w;

#pragma unroll
    for (int c = 0; c < 8; ++c) {
      p[c] += __shfl_xor(p[c], 1);
      p[c] += __shfl_xor(p[c], 2);
      p[c] += __shfl_xor(p[c], 4);
    }
    int v = lane & 7;
    float y = p[0];
    y = (v == 1) ? p[1] : y;
    y = (v == 2) ? p[2] : y;
    y = (v == 3) ? p[3] : y;
    y = (v == 4) ? p[4] : y;
    y = (v == 5) ? p[5] : y;
    y = (v == 6) ? p[6] : y;
    y = (v == 7) ? p[7] : y;
    y += __shfl_xor(y, 8);
    y += __shfl_xor(y, 16);
    y += __shfl_xor(y, 32);
    if (lane < 7) logits[row * 7 + lane] = y;
    else if (lane == 7) an[row] = y;

    int w0 = __builtin_amdgcn_cvt_pk_fp8_f32(v0.x * FP8_SCALE, v0.y * FP8_SCALE, 0, 0);
    w0     = __builtin_amdgcn_cvt_pk_fp8_f32(v0.z * FP8_SCALE, v0.w * FP8_SCALE, w0, 1);
    int w1 = __builtin_amdgcn_cvt_pk_fp8_f32(v1.x * FP8_SCALE, v1.y * FP8_SCALE, 0, 0);
    w1     = __builtin_amdgcn_cvt_pk_fp8_f32(v1.z * FP8_SCALE, v1.w * FP8_SCALE, w1, 1);
    *(int2*)&lrow[rl * 528 + lane * 8] = make_int2(w0, w1);
  }
  __syncthreads();
  int4* outp = (int4*)f8p + (size_t)blockIdx.x * 512;
#pragma unroll
  for (int pi = 0; pi < 2; ++pi) {
    int idx = pi * 256 + t;          // [0,512) = (kp, l)
    int kp = idx >> 6, l = idx & 63;
    int sr = l & 15, qk = l >> 4;
    int2 lo = *(const int2*)&lrow[sr * 528 + kp * 64 + qk * 8];
    int2 hi = *(const int2*)&lrow[sr * 528 + kp * 64 + 32 + qk * 8];
    outp[idx] = make_int4(lo.x, lo.y, hi.x, hi.y);
  }
}

// K1 v9: v8 structure (256x256 tile, 8 waves 2Mx4N, BK=64, dbuf LDS via
// global_load_lds, XCD-clustered grid 648) with the K-tile fragmented into
// 4 SUB-PHASES of 16 MFMA (m201 8-phase shape; m196: fine interleave =
// +28-41% vs coarse): phase p computes A-frag pair {2p,2p+1} x 4 B x {x,y};
// its 2 A ds_reads issue BEFORE its leading barrier (latency hides under
// barrier + prior MFMA); the 4 stage DMAs spread over phases 0-1;
// vmcnt(0) only at the kt boundary (all 4 next-tile loads >=2 phases old).
// Per-accumulator K-order unchanged -> bit-identical output.
__global__ __launch_bounds__(512, 2) void k_gram(const char* __restrict__ f8p,
                                                 const float* __restrict__ an,
                                                 const float* __restrict__ logits,
                                                 float* __restrict__ S,
                                                 float* __restrict__ rs_part,
                                                 float* __restrict__ S1,
                                                 float* __restrict__ S2,
                                                 float* __restrict__ aff) {
  int x = blockIdx.x & 7, u = blockIdx.x >> 3;
  int t = threadIdx.x, lane = t & 63, wave = t >> 6;
  if (blockIdx.x == 0 && t == 0) aff[0] = 0.f;

  if (u == 80) {  // BN stats: 7 blocks (x<7), class x, seg = wave
    if (x >= 7) return;
    int c = x, seg = wave;
    int r0 = seg * 1792;
    float s1 = 0.f, s2 = 0.f;
    for (int j = lane; j < 1792; j += 64) {
      float v = logits[(size_t)(r0 + j) * 7 + c];
      s1 += v;
      s2 += v * v;
    }
#pragma unroll
    for (int o = 1; o < 64; o <<= 1) {
      s1 += __shfl_xor(s1, o);
      s2 += __shfl_xor(s2, o);
    }
    if (lane == 0) { atomicAdd(&S1[c], s1); atomicAdd(&S2[c], s2); }
    return;
  }

  int cls1, cls2, ti, tj, Sidx;
  bool self;
  if (x < 7 && u < 36) {
    int a = 0, r = u;
    while (r > a) { r -= a + 1; ++a; }  // u = a(a+1)/2 + r, r<=a
    ti = a; tj = r;                     // tj <= ti
    cls1 = x; cls2 = x; Sidx = x; self = true;
  } else {
    int j;
    if (x < 7) j = x * 44 + (u - 36);          // 0..307
    else { if (u >= 76) return; j = 308 + u; } // 308..383
    int p = j >> 6, t64 = j & 63;
    ti = t64 >> 3; tj = t64 & 7;
    cls1 = p + 1; cls2 = 0; Sidx = 7 + p; self = false;
  }

  __shared__ char ldsA[2][16384];
  __shared__ char ldsB[2][16384];
  __shared__ float bacc[8];

  int R0 = cls1 * 2048 + ti * 256;
  int C0 = cls2 * 2048 + tj * 256;

  // staging: wave stages chunks {2w, 2w+1} of A and B per K-tile
  const char* gA0 = f8p + ((size_t)(R0 >> 4) + wave * 2)     * 8192 + lane * 16;
  const char* gA1 = f8p + ((size_t)(R0 >> 4) + wave * 2 + 1) * 8192 + lane * 16;
  const char* gB0 = f8p + ((size_t)(C0 >> 4) + wave * 2)     * 8192 + lane * 16;
  const char* gB1 = f8p + ((size_t)(C0 >> 4) + wave * 2 + 1) * 8192 + lane * 16;

  int wr = wave >> 2, wc = wave & 3;   // 2M x 4N wave grid
  int q = lane >> 4, s = lane & 15;

  f32x4 acc[8][4];
#pragma unroll
  for (int i = 0; i < 8; ++i)
#pragma unroll
    for (int j = 0; j < 4; ++j)
      acc[i][j] = (f32x4){0.f, 0.f, 0.f, 0.f};

  // prologue: stage tile 0 fully, drain, publish
  gload16(gA0, &ldsA[0][(wave * 2) * 1024 + lane * 16]);
  gload16(gA1, &ldsA[0][(wave * 2 + 1) * 1024 + lane * 16]);
  gload16(gB0, &ldsB[0][(wave * 2) * 1024 + lane * 16]);
  gload16(gB1, &ldsB[0][(wave * 2 + 1) * 1024 + lane * 16]);
  __syncthreads();

#define MM16(A0_, A1_, I0_, I1_)                                              \
  do {                                                                        \
    asm volatile("s_waitcnt lgkmcnt(0)" ::: "memory");                        \
    __builtin_amdgcn_sched_barrier(0);                                        \
    __builtin_amdgcn_s_setprio(1);                                            \
    _Pragma("unroll")                                                         \
    for (int j_ = 0; j_ < 4; ++j_)                                            \
      acc[I0_][j_] = __builtin_amdgcn_mfma_f32_16x16x32_fp8_fp8(              \
          A0_.x, bb[j_].x, acc[I0_][j_], 0, 0, 0);                            \
    _Pragma("unroll")                                                         \
    for (int j_ = 0; j_ < 4; ++j_)                                            \
      acc[I1_][j_] = __builtin_amdgcn_mfma_f32_16x16x32_fp8_fp8(              \
          A1_.x, bb[j_].x, acc[I1_][j_], 0, 0, 0);                            \
    _Pragma("unroll")                                                         \
    for (int j_ = 0; j_ < 4; ++j_)                                            \
      acc[I0_][j_] = __builtin_amdgcn_mfma_f32_16x16x32_fp8_fp8(              \
          A0_.y, bb[j_].y, acc[I0_][j_], 0, 0, 0);                            \
    _Pragma("unroll")                                                         \
    for (int j_ = 0; j_ < 4; ++j_)                                            \
      acc[I1_][j_] = __builtin_amdgcn_mfma_f32_16x16x32_fp8_fp8(              \
          A1_.y, bb[j_].y, acc[I1_][j_], 0, 0, 0);                            \
    __builtin_amdgcn_s_setprio(0);                                            \
  } while (0)

#pragma unroll 1
  for (int kt = 0; kt < 8; ++kt) {
    int cur = kt & 1;
    const char* LA = &ldsA[cur][(wr * 8) * 1024 + lane * 16];
    const char* LB = &ldsB[cur][(wc * 4) * 1024 + lane * 16];
    longlong2 a0, a1, bb[4];
    // ---- phase 0: i = 0,1 (loads after boundary barrier; buf published) ----
    a0 = *(const longlong2*)(LA);
    a1 = *(const longlong2*)(LA + 1024);
#pragma unroll
    for (int j = 0; j < 4; ++j) bb[j] = *(const longlong2*)(LB + j * 1024);
    if (kt < 7) {  // stage next tile, part 1 (A chunks)
      int nb = cur ^ 1;
      gload16(gA0 + (kt + 1) * 1024, &ldsA[nb][(wave * 2) * 1024 + lane * 16]);
      gload16(gA1 + (kt + 1) * 1024, &ldsA[nb][(wave * 2 + 1) * 1024 + lane * 16]);
    }
    MM16(a0, a1, 0, 1);
    // ---- phase 1: i = 2,3 (ds issued under phase-0 MFMA shadow) ----
    a0 = *(const longlong2*)(LA + 2 * 1024);
    a1 = *(const longlong2*)(LA + 3 * 1024);
    if (kt < 7) {  // stage next tile, part 2 (B chunks)
      int nb = cur ^ 1;
      gload16(gB0 + (kt + 1) * 1024, &ldsB[nb][(wave * 2) * 1024 + lane * 16]);
      gload16(gB1 + (kt + 1) * 1024, &ldsB[nb][(wave * 2 + 1) * 1024 + lane * 16]);
    }
    __builtin_amdgcn_s_barrier();
    asm volatile("" ::: "memory");
    MM16(a0, a1, 2, 3);
    // ---- phase 2: i = 4,5 ----
    a0 = *(const longlong2*)(LA + 4 * 1024);
    a1 = *(const longlong2*)(LA + 5 * 1024);
    __builtin_amdgcn_s_barrier();
    asm volatile("" ::: "memory");
    MM16(a0, a1, 4, 5);
    // ---- phase 3: i = 6,7 ----
    a0 = *(const longlong2*)(LA + 6 * 1024);
    a1 = *(const longlong2*)(LA + 7 * 1024);
    __builtin_amdgcn_s_barrier();
    asm volatile("" ::: "memory");
    MM16(a0, a1, 6, 7);
    // ---- kt boundary: publish next buffer ----
    if (kt < 7)
      asm volatile("s_waitcnt vmcnt(0)" ::: "memory");  // 4 loads, >=2 phases old
    __builtin_amdgcn_s_barrier();
    asm volatile("" ::: "memory");
  }
#undef MM16

  // Epilogue. C/D (16x16x32): col=lane&15, row=(lane>>4)*4+reg.
  bool dg = self && (ti == tj);
  bool mirror = self && (ti > tj);
  float blockAcc = 0.f;
  float colAcc[4] = {0.f, 0.f, 0.f, 0.f};
  float anB_[4];
#pragma unroll
  for (int j = 0; j < 4; ++j) anB_[j] = an[C0 + wc * 64 + j * 16 + s];

#pragma unroll
  for (int i = 0; i < 8; ++i) {
    f32x4 anA_ = *(const f32x4*)&an[R0 + wr * 128 + i * 16 + q * 4];
#pragma unroll
    for (int rg = 0; rg < 4; ++rg) {
      int rl = wr * 128 + i * 16 + q * 4 + rg;
      float aA = anA_[rg];
      float rowAcc = 0.f;
#pragma unroll
      for (int j = 0; j < 4; ++j) {
        int cl = wc * 64 + j * 16 + s;
        float g = acc[i][j][rg];
        float d2 = fmaxf(aA + anB_[j] - g * INV_2S2, 0.f);
        if (dg && rl == cl) d2 = 0.f;  // exact diagonal
        float e1 = __expf(-0.05f * d2);
        float e2 = e1 * e1, e4 = e2 * e2, e8 = e4 * e4, e16 = e8 * e8;
        blockAcc += e1 + e2 + e4 + e8 + e16;
        if (self) {
          float ek = __expf(-12.5f * d2);  // KDE: 1/(2*0.2^2)
          rowAcc += ek;
          if (mirror) colAcc[j] += ek;
        }
      }
      if (self) {
        rowAcc += __shfl_xor(rowAcc, 1);
        rowAcc += __shfl_xor(rowAcc, 2);
        rowAcc += __shfl_xor(rowAcc, 4);
        rowAcc += __shfl_xor(rowAcc, 8);
        if (s == 0)
          rs_part[(size_t)(R0 + rl) * 48 + tj * 4 + wc] = rowAcc;
      }
    }
  }
  if (mirror) {
#pragma unroll
    for (int j = 0; j < 4; ++j) {
      float v = colAcc[j];
      v += __shfl_xor(v, 16);
      v += __shfl_xor(v, 32);
      if (q == 0)
        rs_part[(size_t)(C0 + wc * 64 + j * 16 + s) * 48 + 32 + ti * 2 + wr] = v;
    }
    blockAcc *= 2.f;  // mirror tile counted once
  }
#pragma unroll
  for (int o = 1; o < 64; o <<= 1) blockAcc += __shfl_xor(blockAcc, o);
  if (lane == 0) bacc[wave] = blockAcc;
  __syncthreads();
  if (t == 0) {
    float sB = 0.f;
#pragma unroll
    for (int w = 0; w < 8; ++w) sB += bacc[w];
    atomicAdd(&S[Sidx], sB);
  }
}

// K2: bnout (blocks 0..97, 1024 thr) + per-class KDE weight & affinity
// (blocks 98..104). Reads only the valid rs_part slots per block-row bi:
// direct [0, 4bi+4), mirror [34+2bi, 48).
__global__ __launch_bounds__(1024) void k_final(const float* __restrict__ logits,
                                                const float* __restrict__ S1,
                                                const float* __restrict__ S2,
                                                const float* __restrict__ gamma,
                                                const float* __restrict__ beta,
                                                const float* __restrict__ rs_part,
                                                const float* __restrict__ S,
                                                float* __restrict__ out) {
  int b = blockIdx.x, t = threadIdx.x;
  if (b < 98) {
    int idx = b * 1024 + t;  // 98*1024 = 100352 exactly
    int row = idx / 7;
    int c = idx - row * 7;
    float mu = S1[c] * (1.f / 14336.f);
    float var = S2[c] * (1.f / 14336.f) - mu * mu;
    out[idx] = gamma[c] * (logits[idx] - mu) * rsqrtf(var + 1e-5f) + beta[c];
    return;
  }
  int c = b - 98;
  // log_norm = -256*ln(2*pi*0.04) - ln(2048)
  const float LOG_NORM = 345.9110632f;
  float v = 0.f;
  for (int i = t; i < M_CLS; i += 1024) {
    int bi = i >> 8;
    const float* rp = rs_part + (size_t)(c * M_CLS + i) * 48;
    float rsum = 0.f;
    int nd = 4 * bi + 4;
    for (int k = 0; k < nd; ++k) rsum += rp[k];
    for (int k = 34 + 2 * bi; k < 48; ++k) rsum += rp[k];
    v += 1.f / (logf(rsum) + LOG_NORM);
  }
#pragma unroll
  for (int o = 1; o < 64; o <<= 1) v += __shfl_xor(v, o);
  __shared__ float r[16];
  if ((t & 63) == 0) r[t >> 6] = v;
  __syncthreads();
  if (t == 0) {
    float vs = 0.f;
#pragma unroll
    for (int w = 0; w < 16; ++w) vs += r[w];
    float w = 1.f / (vs + 1e-5f);
    const float inv_m2 = 1.0f / ((float)M_CLS * (float)M_CLS);
    float Ssrc = S[c];
    float Stgt = (c > 0) ? S[0] : S[1];
    float X    = (c > 0) ? S[6 + c] : S[7];  // cross Sidx 7+p is (p+1,0)
    float mmd = (Ssrc + Stgt - 2.f * X) * inv_m2;
    atomicAdd(&out[100352], -mmd * w);
  }
}

extern "C" void kernel_launch(void* const* d_in, const int* in_sizes, int n_in,
                              void* d_out, int out_size, void* d_ws, size_t ws_size,
                              hipStream_t stream) {
  const float* fea   = (const float*)d_in[0];
  const float* W_fc  = (const float*)d_in[1];
  const float* gamma = (const float*)d_in[2];
  const float* beta  = (const float*)d_in[3];
  float* out = (float*)d_out;

  char* ws = (char*)d_ws;
  char* f8p = ws;                                // packed fp8 image: 7,340,032 B
  float* fbase   = (float*)(ws + 7340032);
  float* an      = fbase;                        // 14336
  float* logits  = fbase + 14336;                // 100352
  float* zb      = fbase + 114688;               // 64-float zero block
  float* S1      = zb;                           //   [0..6]
  float* S2      = zb + 7;                       //   [7..13]
  float* S       = zb + 16;                      //   [16..28] (13 used)
  float* rs_part = fbase + 114752;               // 14336*48 (valid slots only)

  k_prep <<<896, 256, 0, stream>>>(fea, W_fc, f8p, an, logits, zb);
  k_gram <<<648, 512, 0, stream>>>(f8p, an, logits, S, rs_part, S1, S2,
                                   out + 100352);
  k_final<<<105, 1024, 0, stream>>>(logits, S1, S2, gamma, beta, rs_part, S, out);
}